// Round 6
// baseline (325.752 us; speedup 1.0000x reference)
//
#include <hip/hip_runtime.h>
#include <hip/hip_bf16.h>

// Problem constants (from reference setup_inputs)
#define D     128
#define K0    50
#define NCOL  51      // output columns: 50 (centers0) + 1 (centers1)
#define NT    12      // 192 GEMM cols = 8 z_rot tiles + 4 cross tiles
#define TB    128     // batch rows per block (2 row-tiles per wave)

typedef __attribute__((ext_vector_type(4))) float  f32x4;
typedef __attribute__((ext_vector_type(8))) short  short8x;  // 8 bf16 in 4 VGPRs

__device__ inline short f2bf(float x) {
    __hip_bfloat16 h = __float2bfloat16(x);
    return __builtin_bit_cast(short, h);
}

// ---------------------------------------------------------------------------
// Setup: build G (128 x 192) in bf16 MFMA fragment order:
//   Gws[blk=(ks*12+nt)][lane][j] = G[ks*32+(lane>>4)*8+j][nt*16+(lane&15)]
//   tiles 0..7  : V * diag(sqrt(beta0))  (z_rot pre-scaled so zz0 = sum y^2)
//   tiles 8..11 : -2 * M, M[:,k] = V (beta . c_k)
// Block 48: cc[k] (beta-weighted center norms, [64] zero-padded) + beta0 dump.
// ---------------------------------------------------------------------------
__global__ __launch_bounds__(128) void setup_kernel(
    const float* __restrict__ bw,   // [2][128]
    const float* __restrict__ V,    // [128][128]
    const float* __restrict__ c0,   // [50][128]
    const float* __restrict__ c1,   // [1][128]
    short* __restrict__ Gws,        // bf16 frag layout [48][64][8]
    float* __restrict__ ccws,       // [64] (51 used, rest zero)
    float* __restrict__ betaws)     // [128]
{
    const int blk = blockIdx.x;
    const int t   = threadIdx.x;
    __shared__ float beta0[D];
    __shared__ float Vt[D * 33];    // V[ks*32+d][e] transposed -> Vt[e*33+d]
    __shared__ float wct[D * 17];   // (beta.c)[k][e] transposed -> wct[e*17+k]

    if (t < D) {
        float b0 = bw[t], b1 = bw[D + t];
        beta0[t] = 1.0f / (1.0f + expf(b1 - b0));   // softmax over axis 0
    }
    __syncthreads();

    if (blk == 48) {                 // cc terms + beta float dump
        if (t < D) betaws[t] = beta0[t];
        if (t >= NCOL && t < 64) ccws[t] = 0.f;     // clean tail (k=51..63)
        if (t < NCOL) {
            const float* cr = (t < K0) ? (c0 + (size_t)t * D) : c1;
            float s = 0.f;
            for (int e = 0; e < D; ++e) {
                float b = (t == K0) ? (1.0f - beta0[e]) : beta0[e];
                float cv = cr[e];
                s += b * cv * cv;
            }
            ccws[t] = s;
        }
        return;
    }

    const int kstep = blk / NT;      // 0..3
    const int ntile = blk % NT;      // 0..11
    const int lane  = t >> 1;
    const int jbase = (t & 1) * 4;
    const int nl    = lane & 15;

    if (ntile < 8) {                 // G col = V col * sqrt(beta0[col])
        const int n = ntile * 16 + nl;
        const float sb = sqrtf(beta0[n]);
        short* dst = Gws + ((size_t)(blk * 64 + lane)) * 8 + jbase;
        for (int jj = 0; jj < 4; ++jj) {
            int d = kstep * 32 + (lane >> 4) * 8 + jbase + jj;
            dst[jj] = f2bf(V[(size_t)d * D + n] * sb);
        }
        return;
    }

    // cross tiles: stage V rows (transposed) and beta-weighted centers
    for (int i = t; i < 32 * D; i += 128) {
        int d = i >> 7, e = i & 127;              // consecutive t -> consecutive e
        Vt[e * 33 + d] = V[(size_t)(kstep * 32 + d) * D + e];
    }
    for (int i = t; i < 16 * D; i += 128) {
        int kl = i >> 7, e = i & 127;
        int k = (ntile - 8) * 16 + kl;
        float w = 0.f;
        if (k < K0)       w = beta0[e] * c0[(size_t)k * D + e];
        else if (k == K0) w = (1.0f - beta0[e]) * c1[e];
        wct[e * 17 + kl] = w;
    }
    __syncthreads();

    short res[4];
    for (int jj = 0; jj < 4; ++jj) {
        int dl = (lane >> 4) * 8 + jbase + jj;    // 0..31
        float s = 0.f;
        #pragma unroll 8
        for (int e = 0; e < D; ++e)
            s += Vt[e * 33 + dl] * wct[e * 17 + nl];   // bank-conflict-free
        res[jj] = f2bf(-2.0f * s);                     // fold -2x into G
    }
    short* dst = Gws + ((size_t)(blk * 64 + lane)) * 8 + jbase;
    for (int jj = 0; jj < 4; ++jj) dst[jj] = res[jj];
}

// ---------------------------------------------------------------------------
// Main: per block, 128 rows (2 row-tiles of 16 per wave). (256,3), 48KB LDS,
// no spill (R5: VGPR=84). R6 changes, driven by R5's WRITE=255MB (4.8x amp)
// and FETCH=268MB (2x):
//  (a) cross MFMA transposed: mfma(zfrag, crossfrag) -> C[row=batch(q*4+r)]
//      [col=k(c)]. Stores become 64-B contiguous runs per row (lanes c=0..15
//      write 16 consecutive dwords), full sectors after j-merge in L2 —
//      kills the 4-B/204-B-stride scatter. Also deletes the zz0
//      redistribution shuffles entirely (qp[r] post-reduce IS zz0 for row
//      q*4+r, matching the new store row mapping).
//  (b) z loads via __builtin_nontemporal_load: z is read-once; nt stops z
//      from evicting the 48KB G working set out of L2, so each block's G
//      staging re-read is an L2 hit instead of ~100MB of HBM/L3 fetch.
// cc[k] folded into the accc C-init (splat of ccws[j*16+c]).
// ---------------------------------------------------------------------------
__global__ __launch_bounds__(256, 3) void main_kernel(
    const float* __restrict__ z,      // [B][128]
    const short* __restrict__ Gws,    // bf16 frag layout [48][64][8]
    const float* __restrict__ ccws,   // [64]
    const float* __restrict__ betaws, // [128] (unused; beta folded into G)
    float* __restrict__ out)          // [B][51]
{
    __shared__ __align__(16) short Gs[48 * 64 * 8];  // 49152 B -> 3 blocks/CU

    const int t    = threadIdx.x;
    const int wave = t >> 6;
    const int lane = t & 63;
    const int c    = lane & 15;
    const int q    = lane >> 4;
    const size_t rowbase = (size_t)blockIdx.x * TB;

    // ---- stage G (48 KB; L2-resident thanks to nt z-loads) ----
    for (int i = t; i < 48 * 64 * 8 / 8; i += 256)
        ((int4*)Gs)[i] = ((const int4*)Gws)[i];

    // per-lane cc for k = j*16+c (loop-invariant; zero-padded past 50)
    float ccreg[4];
    #pragma unroll
    for (int j = 0; j < 4; ++j) ccreg[j] = ccws[j * 16 + c];
    __syncthreads();

    for (int rt = 0; rt < 2; ++rt) {
        const int rowloc = (wave * 2 + rt) * 16;
        const float* zrow = z + (rowbase + rowloc + c) * D;

        // z fragments (lane holds A[m=c][k=q*8+..]); exact |z|^2 on the fly
        short8x zfrag[4];
        float nrm_p = 0.f;
        #pragma unroll
        for (int ks = 0; ks < 4; ++ks) {
            const float* p = zrow + ks * 32 + q * 8;
            f32x4 v0 = __builtin_nontemporal_load((const f32x4*)p);
            f32x4 v1 = __builtin_nontemporal_load((const f32x4*)(p + 4));
            nrm_p += v0.x*v0.x + v0.y*v0.y + v0.z*v0.z + v0.w*v0.w
                   + v1.x*v1.x + v1.y*v1.y + v1.z*v1.z + v1.w*v1.w;
            short8x a;
            a[0] = f2bf(v0.x); a[1] = f2bf(v0.y); a[2] = f2bf(v0.z); a[3] = f2bf(v0.w);
            a[4] = f2bf(v1.x); a[5] = f2bf(v1.y); a[6] = f2bf(v1.z); a[7] = f2bf(v1.w);
            zfrag[ks] = a;
        }

        // cross accumulators init = cc[k=j*16+c] (same for all q,r at fixed c)
        f32x4 accc[4];
        #pragma unroll
        for (int j = 0; j < 4; ++j)
            accc[j] = f32x4{ccreg[j], ccreg[j], ccreg[j], ccreg[j]};

        // ---- cross tiles as B-operand: C[row=batch(q*4+r)][col=k(c)] ----
        #pragma unroll
        for (int j = 0; j < 4; ++j) {
            #pragma unroll
            for (int ks = 0; ks < 4; ++ks) {
                short8x bfrg = *(const short8x*)&Gs[((ks * NT + 8 + j) * 64 + lane) * 8];
                accc[j] = __builtin_amdgcn_mfma_f32_16x16x32_bf16(zfrag[ks], bfrg, accc[j], 0, 0, 0);
            }
        }

        // ---- z_rot tiles (sqrt(beta) pre-folded), nt-outer / ks-inner ----
        // C layout: row=batch(q*4+r), col=feature(nt*16+c)
        float qp[4] = {0.f, 0.f, 0.f, 0.f};
        #pragma unroll
        for (int nt = 0; nt < 8; ++nt) {
            f32x4 acc = f32x4{0.f, 0.f, 0.f, 0.f};
            #pragma unroll
            for (int ks = 0; ks < 4; ++ks) {
                short8x bfrg = *(const short8x*)&Gs[((ks * NT + nt) * 64 + lane) * 8];
                acc = __builtin_amdgcn_mfma_f32_16x16x32_bf16(zfrag[ks], bfrg, acc, 0, 0, 0);
            }
            #pragma unroll
            for (int r = 0; r < 4; ++r) {
                float y = acc[r];
                qp[r] += y * y;                // beta already inside G
            }
        }

        // ---- zz0: reduce over the 16 feature-lanes (c bits) ----
        // After this, qp[r] = zz0 for batch row q*4+r — matches store rows.
        #pragma unroll
        for (int s = 1; s < 16; s <<= 1) {
            #pragma unroll
            for (int r = 0; r < 4; ++r) qp[r] += __shfl_xor(qp[r], s, 64);
        }
        // exact |z|^2 for row c (sum over the 4 q-chunks)...
        float nrm = nrm_p + __shfl_xor(nrm_p, 16, 64);
        nrm += __shfl_xor(nrm, 32, 64);
        // ...gathered to row q*4+r indexing (source lane q*4+r holds row q*4+r)
        float nrmv[4];
        #pragma unroll
        for (int r = 0; r < 4; ++r) nrmv[r] = __shfl(nrm, q * 4 + r, 64);

        // ---- coalesced stores: lanes c=0..15 -> 16 contiguous dwords/row ----
        #pragma unroll
        for (int r = 0; r < 4; ++r) {
            float* orow = out + (rowbase + rowloc + q * 4 + r) * (size_t)NCOL;
            #pragma unroll
            for (int j = 0; j < 3; ++j)        // k = 0..47
                orow[j * 16 + c] = qp[r] + accc[j][r];
            // k = 48,49 (zz0-based) and 50 (zz1-based); lanes c>=3 idle
            float v = (c == 2) ? (nrmv[r] - qp[r]) + accc[3][r]
                               : qp[r] + accc[3][r];
            if (c < 3) orow[48 + c] = v;
        }
    }
}

extern "C" void kernel_launch(void* const* d_in, const int* in_sizes, int n_in,
                              void* d_out, int out_size, void* d_ws, size_t ws_size,
                              hipStream_t stream) {
    const float* z  = (const float*)d_in[0];
    const float* bw = (const float*)d_in[1];
    const float* V  = (const float*)d_in[2];
    const float* c0 = (const float*)d_in[3];
    const float* c1 = (const float*)d_in[4];
    float* out = (float*)d_out;

    short* Gws    = (short*)d_ws;                                  // 49152 B
    float* ccws   = (float*)((char*)d_ws + 48 * 64 * 8 * 2);       // 64 floats
    float* betaws = ccws + 64;                                     // 128 floats

    const int B = in_sizes[0] / D;   // 262144

    setup_kernel<<<49, 128, 0, stream>>>(bw, V, c0, c1, Gws, ccws, betaws);
    main_kernel<<<B / TB, 256, 0, stream>>>(z, Gws, ccws, betaws, out);
}

// Round 7
// 299.181 us; speedup vs baseline: 1.0888x; 1.0888x over previous
//
#include <hip/hip_runtime.h>
#include <hip/hip_bf16.h>

// Problem constants (from reference setup_inputs)
#define D     128
#define K0    50
#define NCOL  51      // output columns: 50 (centers0) + 1 (centers1)
#define NT    12      // 192 GEMM cols = 8 z_rot tiles + 4 cross tiles
#define TB    128     // batch rows per block (128*204B = 26112B out tile,
                      // 128-B aligned, fits in the reused 48KB G buffer)

typedef __attribute__((ext_vector_type(4))) float  f32x4;
typedef __attribute__((ext_vector_type(8))) short  short8x;  // 8 bf16 in 4 VGPRs

__device__ inline short f2bf(float x) {
    __hip_bfloat16 h = __float2bfloat16(x);
    return __builtin_bit_cast(short, h);
}

// ---------------------------------------------------------------------------
// Setup: build G (128 x 192) in bf16 MFMA fragment order:
//   Gws[blk=(ks*12+nt)][lane][j] = G[ks*32+(lane>>4)*8+j][nt*16+(lane&15)]
//   tiles 0..7  : V * diag(sqrt(beta0))  (z_rot pre-scaled so zz0 = sum y^2)
//   tiles 8..11 : -2 * M, M[:,k] = V (beta . c_k)
// Block 48: cc[k] (beta-weighted center norms, [64] zero-padded) + beta0 dump.
// ---------------------------------------------------------------------------
__global__ __launch_bounds__(128) void setup_kernel(
    const float* __restrict__ bw,   // [2][128]
    const float* __restrict__ V,    // [128][128]
    const float* __restrict__ c0,   // [50][128]
    const float* __restrict__ c1,   // [1][128]
    short* __restrict__ Gws,        // bf16 frag layout [48][64][8]
    float* __restrict__ ccws,       // [64] (51 used, rest zero)
    float* __restrict__ betaws)     // [128]
{
    const int blk = blockIdx.x;
    const int t   = threadIdx.x;
    __shared__ float beta0[D];
    __shared__ float Vt[D * 33];    // V[ks*32+d][e] transposed -> Vt[e*33+d]
    __shared__ float wct[D * 17];   // (beta.c)[k][e] transposed -> wct[e*17+k]

    if (t < D) {
        float b0 = bw[t], b1 = bw[D + t];
        beta0[t] = 1.0f / (1.0f + expf(b1 - b0));   // softmax over axis 0
    }
    __syncthreads();

    if (blk == 48) {                 // cc terms + beta float dump
        if (t < D) betaws[t] = beta0[t];
        if (t >= NCOL && t < 64) ccws[t] = 0.f;     // clean tail (k=51..63)
        if (t < NCOL) {
            const float* cr = (t < K0) ? (c0 + (size_t)t * D) : c1;
            float s = 0.f;
            for (int e = 0; e < D; ++e) {
                float b = (t == K0) ? (1.0f - beta0[e]) : beta0[e];
                float cv = cr[e];
                s += b * cv * cv;
            }
            ccws[t] = s;
        }
        return;
    }

    const int kstep = blk / NT;      // 0..3
    const int ntile = blk % NT;      // 0..11
    const int lane  = t >> 1;
    const int jbase = (t & 1) * 4;
    const int nl    = lane & 15;

    if (ntile < 8) {                 // G col = V col * sqrt(beta0[col])
        const int n = ntile * 16 + nl;
        const float sb = sqrtf(beta0[n]);
        short* dst = Gws + ((size_t)(blk * 64 + lane)) * 8 + jbase;
        for (int jj = 0; jj < 4; ++jj) {
            int d = kstep * 32 + (lane >> 4) * 8 + jbase + jj;
            dst[jj] = f2bf(V[(size_t)d * D + n] * sb);
        }
        return;
    }

    // cross tiles: stage V rows (transposed) and beta-weighted centers
    for (int i = t; i < 32 * D; i += 128) {
        int d = i >> 7, e = i & 127;              // consecutive t -> consecutive e
        Vt[e * 33 + d] = V[(size_t)(kstep * 32 + d) * D + e];
    }
    for (int i = t; i < 16 * D; i += 128) {
        int kl = i >> 7, e = i & 127;
        int k = (ntile - 8) * 16 + kl;
        float w = 0.f;
        if (k < K0)       w = beta0[e] * c0[(size_t)k * D + e];
        else if (k == K0) w = (1.0f - beta0[e]) * c1[e];
        wct[e * 17 + kl] = w;
    }
    __syncthreads();

    short res[4];
    for (int jj = 0; jj < 4; ++jj) {
        int dl = (lane >> 4) * 8 + jbase + jj;    // 0..31
        float s = 0.f;
        #pragma unroll 8
        for (int e = 0; e < D; ++e)
            s += Vt[e * 33 + dl] * wct[e * 17 + nl];   // bank-conflict-free
        res[jj] = f2bf(-2.0f * s);                     // fold -2x into G
    }
    short* dst = Gws + ((size_t)(blk * 64 + lane)) * 8 + jbase;
    for (int jj = 0; jj < 4; ++jj) dst[jj] = res[jj];
}

// ---------------------------------------------------------------------------
// Main, R7: kill the partial-line write amplification (R5/R6: WRITE 255-275MB
// vs 53.5MB real, FETCH +~130MB of write-allocate RMW — 204-B rows mean no
// store instruction ever covers a full 128-B line; TCC assembles each line
// over ~5 evict+refetch rounds under thrash).
// Fix: compute BOTH 16-row phases per wave holding results in registers
// (acccA/B 32 regs + qpA/B + nrmA/B; VGPR ~110 « the (256,3) 170 cap, no
// spill), then __syncthreads — G is now dead — REUSE the 48KB Gs buffer as a
// [128][51] f32 staging tile, then cooperatively flush 26112 B with int4
// stores: 64 lanes x 16 B = 1KB contiguous per instruction, and the block's
// out region is 128-B aligned (26112 = 204 lines exactly) -> every line
// fully covered by a single instruction -> writeback = real output only,
// no RMW fetches. Cross MFMA stays transposed (C[row=batch][col=k], R6) so
// staging writes are simple dword scatters (<=3-way LDS bank alias, ~free).
// ---------------------------------------------------------------------------
__global__ __launch_bounds__(256, 3) void main_kernel(
    const float* __restrict__ z,      // [B][128]
    const short* __restrict__ Gws,    // bf16 frag layout [48][64][8]
    const float* __restrict__ ccws,   // [64]
    const float* __restrict__ betaws, // [128] (unused; beta folded into G)
    float* __restrict__ out)          // [B][51]
{
    __shared__ __align__(16) short Gs[48 * 64 * 8];  // 49152 B; reused as out-stage

    const int t    = threadIdx.x;
    const int wave = t >> 6;
    const int lane = t & 63;
    const int c    = lane & 15;
    const int q    = lane >> 4;
    const size_t rowbase = (size_t)blockIdx.x * TB;

    // ---- stage G (48 KB, L2/L3-resident source) ----
    for (int i = t; i < 48 * 64 * 8 / 8; i += 256)
        ((int4*)Gs)[i] = ((const int4*)Gws)[i];

    // per-lane cc for k = j*16+c (loop-invariant; zero-padded past 50)
    float ccreg[4];
    #pragma unroll
    for (int j = 0; j < 4; ++j) ccreg[j] = ccws[j * 16 + c];
    __syncthreads();

    f32x4 acccA[4], acccB[4];
    float qpA[4], qpB[4], nrmA[4], nrmB[4];

    // ================= phase A: rows wave*32 + 0..15 =================
    {
        const int rowloc = wave * 32;
        const float* zrow = z + (rowbase + rowloc + c) * D;
        short8x zfrag[4];
        float nrm_p = 0.f;
        #pragma unroll
        for (int ks = 0; ks < 4; ++ks) {
            const float* p = zrow + ks * 32 + q * 8;
            f32x4 v0 = *(const f32x4*)p;
            f32x4 v1 = *(const f32x4*)(p + 4);
            nrm_p += v0.x*v0.x + v0.y*v0.y + v0.z*v0.z + v0.w*v0.w
                   + v1.x*v1.x + v1.y*v1.y + v1.z*v1.z + v1.w*v1.w;
            short8x a;
            a[0] = f2bf(v0.x); a[1] = f2bf(v0.y); a[2] = f2bf(v0.z); a[3] = f2bf(v0.w);
            a[4] = f2bf(v1.x); a[5] = f2bf(v1.y); a[6] = f2bf(v1.z); a[7] = f2bf(v1.w);
            zfrag[ks] = a;
        }
        #pragma unroll
        for (int j = 0; j < 4; ++j)
            acccA[j] = f32x4{ccreg[j], ccreg[j], ccreg[j], ccreg[j]};
        #pragma unroll
        for (int j = 0; j < 4; ++j) {
            #pragma unroll
            for (int ks = 0; ks < 4; ++ks) {
                short8x bfrg = *(const short8x*)&Gs[((ks * NT + 8 + j) * 64 + lane) * 8];
                acccA[j] = __builtin_amdgcn_mfma_f32_16x16x32_bf16(zfrag[ks], bfrg, acccA[j], 0, 0, 0);
            }
        }
        float qp[4] = {0.f, 0.f, 0.f, 0.f};
        #pragma unroll
        for (int nt = 0; nt < 8; ++nt) {
            f32x4 acc = f32x4{0.f, 0.f, 0.f, 0.f};
            #pragma unroll
            for (int ks = 0; ks < 4; ++ks) {
                short8x bfrg = *(const short8x*)&Gs[((ks * NT + nt) * 64 + lane) * 8];
                acc = __builtin_amdgcn_mfma_f32_16x16x32_bf16(zfrag[ks], bfrg, acc, 0, 0, 0);
            }
            #pragma unroll
            for (int r = 0; r < 4; ++r) { float y = acc[r]; qp[r] += y * y; }
        }
        #pragma unroll
        for (int s = 1; s < 16; s <<= 1) {
            #pragma unroll
            for (int r = 0; r < 4; ++r) qp[r] += __shfl_xor(qp[r], s, 64);
        }
        float nrm = nrm_p + __shfl_xor(nrm_p, 16, 64);
        nrm += __shfl_xor(nrm, 32, 64);
        #pragma unroll
        for (int r = 0; r < 4; ++r) {
            qpA[r]  = qp[r];
            nrmA[r] = __shfl(nrm, q * 4 + r, 64);
        }
    }

    // ================= phase B: rows wave*32 + 16..31 =================
    {
        const int rowloc = wave * 32 + 16;
        const float* zrow = z + (rowbase + rowloc + c) * D;
        short8x zfrag[4];
        float nrm_p = 0.f;
        #pragma unroll
        for (int ks = 0; ks < 4; ++ks) {
            const float* p = zrow + ks * 32 + q * 8;
            f32x4 v0 = *(const f32x4*)p;
            f32x4 v1 = *(const f32x4*)(p + 4);
            nrm_p += v0.x*v0.x + v0.y*v0.y + v0.z*v0.z + v0.w*v0.w
                   + v1.x*v1.x + v1.y*v1.y + v1.z*v1.z + v1.w*v1.w;
            short8x a;
            a[0] = f2bf(v0.x); a[1] = f2bf(v0.y); a[2] = f2bf(v0.z); a[3] = f2bf(v0.w);
            a[4] = f2bf(v1.x); a[5] = f2bf(v1.y); a[6] = f2bf(v1.z); a[7] = f2bf(v1.w);
            zfrag[ks] = a;
        }
        #pragma unroll
        for (int j = 0; j < 4; ++j)
            acccB[j] = f32x4{ccreg[j], ccreg[j], ccreg[j], ccreg[j]};
        #pragma unroll
        for (int j = 0; j < 4; ++j) {
            #pragma unroll
            for (int ks = 0; ks < 4; ++ks) {
                short8x bfrg = *(const short8x*)&Gs[((ks * NT + 8 + j) * 64 + lane) * 8];
                acccB[j] = __builtin_amdgcn_mfma_f32_16x16x32_bf16(zfrag[ks], bfrg, acccB[j], 0, 0, 0);
            }
        }
        float qp[4] = {0.f, 0.f, 0.f, 0.f};
        #pragma unroll
        for (int nt = 0; nt < 8; ++nt) {
            f32x4 acc = f32x4{0.f, 0.f, 0.f, 0.f};
            #pragma unroll
            for (int ks = 0; ks < 4; ++ks) {
                short8x bfrg = *(const short8x*)&Gs[((ks * NT + nt) * 64 + lane) * 8];
                acc = __builtin_amdgcn_mfma_f32_16x16x32_bf16(zfrag[ks], bfrg, acc, 0, 0, 0);
            }
            #pragma unroll
            for (int r = 0; r < 4; ++r) { float y = acc[r]; qp[r] += y * y; }
        }
        #pragma unroll
        for (int s = 1; s < 16; s <<= 1) {
            #pragma unroll
            for (int r = 0; r < 4; ++r) qp[r] += __shfl_xor(qp[r], s, 64);
        }
        float nrm = nrm_p + __shfl_xor(nrm_p, 16, 64);
        nrm += __shfl_xor(nrm, 32, 64);
        #pragma unroll
        for (int r = 0; r < 4; ++r) {
            qpB[r]  = qp[r];
            nrmB[r] = __shfl(nrm, q * 4 + r, 64);
        }
    }

    // ---- G is dead: reuse Gs as [128][51] f32 out-staging tile ----
    __syncthreads();
    float* outs = (float*)Gs;

    #pragma unroll
    for (int r = 0; r < 4; ++r) {              // phase A rows
        const int row = wave * 32 + q * 4 + r;
        #pragma unroll
        for (int j = 0; j < 3; ++j)
            outs[row * NCOL + j * 16 + c] = qpA[r] + acccA[j][r];
        if (c < 3) {
            float v = (c == 2) ? (nrmA[r] - qpA[r]) + acccA[3][r]
                               : qpA[r] + acccA[3][r];
            outs[row * NCOL + 48 + c] = v;
        }
    }
    #pragma unroll
    for (int r = 0; r < 4; ++r) {              // phase B rows
        const int row = wave * 32 + 16 + q * 4 + r;
        #pragma unroll
        for (int j = 0; j < 3; ++j)
            outs[row * NCOL + j * 16 + c] = qpB[r] + acccB[j][r];
        if (c < 3) {
            float v = (c == 2) ? (nrmB[r] - qpB[r]) + acccB[3][r]
                               : qpB[r] + acccB[3][r];
            outs[row * NCOL + 48 + c] = v;
        }
    }
    __syncthreads();

    // ---- full-line flush: 26112 B = 1632 int4; 1 KB contiguous per instr ----
    int4* dst = (int4*)(out + rowbase * NCOL);   // 128-B aligned (26112*blk)
    const int4* src = (const int4*)outs;
    for (int i = t; i < TB * NCOL / 4; i += 256)
        dst[i] = src[i];
}

extern "C" void kernel_launch(void* const* d_in, const int* in_sizes, int n_in,
                              void* d_out, int out_size, void* d_ws, size_t ws_size,
                              hipStream_t stream) {
    const float* z  = (const float*)d_in[0];
    const float* bw = (const float*)d_in[1];
    const float* V  = (const float*)d_in[2];
    const float* c0 = (const float*)d_in[3];
    const float* c1 = (const float*)d_in[4];
    float* out = (float*)d_out;

    short* Gws    = (short*)d_ws;                                  // 49152 B
    float* ccws   = (float*)((char*)d_ws + 48 * 64 * 8 * 2);       // 64 floats
    float* betaws = ccws + 64;                                     // 128 floats

    const int B = in_sizes[0] / D;   // 262144

    setup_kernel<<<49, 128, 0, stream>>>(bw, V, c0, c1, Gws, ccws, betaws);
    main_kernel<<<B / TB, 256, 0, stream>>>(z, Gws, ccws, betaws, out);
}